// Round 21
// baseline (401.032 us; speedup 1.0000x reference)
//
#include <hip/hip_runtime.h>
#include <hip/hip_fp16.h>
#include <hip/hip_fp8.h>

#define HEADS 2
#define DD 128
#define FF 16
#define HD 256  // HEADS*DD
#define NEG_SLOPE 0.2f
#define EPSV 1e-16f
#define BB 8
#define DBINS 1024

typedef float v2f __attribute__((ext_vector_type(2)));

static __device__ __forceinline__ float rdlanef(float v, int i){
  return __uint_as_float(__builtin_amdgcn_readlane(__float_as_uint(v), i));
}
static __device__ __forceinline__ int rdlanei(int v, int i){
  return __builtin_amdgcn_readlane(v, i);
}
static __device__ __forceinline__ float4 h4f(uint2 u){
  float2 f0 = __half22float2(*(__half2*)&u.x);
  float2 f1 = __half22float2(*(__half2*)&u.y);
  return make_float4(f0.x, f0.y, f1.x, f1.y);
}
static __device__ __forceinline__ float4 fp8x4_to_f4(unsigned u){
#if __has_builtin(__builtin_amdgcn_cvt_pk_f32_fp8)
  v2f lo = __builtin_amdgcn_cvt_pk_f32_fp8(u, false);   // bytes 0,1
  v2f hi = __builtin_amdgcn_cvt_pk_f32_fp8(u, true);    // bytes 2,3
  return make_float4(lo.x, lo.y, hi.x, hi.y);
#else
  __hip_fp8_e4m3 b0, b1, b2, b3;
  b0.__x = (unsigned char)(u & 0xff);
  b1.__x = (unsigned char)((u >> 8) & 0xff);
  b2.__x = (unsigned char)((u >> 16) & 0xff);
  b3.__x = (unsigned char)((u >> 24) & 0xff);
  return make_float4((float)b0, (float)b1, (float)b2, (float)b3);
#endif
}

// ---------------- CSR build ----------------
// blocks [0,ebl): dst histogram. [ebl,ebl+5): c5 constants. [ebl+5,ebl+165): W->fp16.
__global__ void k_hist_prec(const int* __restrict__ dst, int* __restrict__ counts,
                            const float* __restrict__ atts, const float* __restrict__ edge_ws,
                            const float* __restrict__ edge_bs, const float* __restrict__ weights,
                            float* __restrict__ c5, __half* __restrict__ wh,
                            int E, int Etot, int ebl){
  int bid = blockIdx.x;
  if (bid >= ebl){
    int k = bid - ebl;
    if (k < 5){
      int l = k, t = threadIdx.x;
      const float* att = atts    + (size_t)l*HEADS*2*DD;
      const float* ew  = edge_ws + (size_t)l*HD*FF;
      const float* eb  = edge_bs + (size_t)l*HD;
      float* c = c5 + (size_t)l*34;
      if (t < 32){
        int h = t >> 4, f = t & 15;
        float acc = 0.f;
        for (int d = 0; d < DD; d++) acc += att[h*2*DD + DD + d]*ew[(size_t)(h*DD+d)*FF + f];
        c[h*FF + f] = acc;
      } else if (t < 34){
        int h = t - 32;
        float acc = 0.f;
        for (int d = 0; d < DD; d++) acc += att[h*2*DD + DD + d]*eb[h*DD + d];
        c[32 + h] = acc;
      }
    } else {
      int base = (k - 5)*1024 + threadIdx.x*4;   // 5*DD*HD = 163840 = 160*1024
      float4 w = *(const float4*)&weights[base];
      __half2 p0 = __floats2half2_rn(w.x, w.y);
      __half2 p1 = __floats2half2_rn(w.z, w.w);
      uint2 pk; pk.x = *(unsigned*)&p0; pk.y = *(unsigned*)&p1;
      *(uint2*)&wh[base] = pk;
    }
    return;
  }
  int e = bid*256 + threadIdx.x;
  if (e >= Etot) return;
  int dn = (e < E) ? dst[e] : (e - E);
  atomicAdd(&counts[dn], 1);
}

__global__ __launch_bounds__(1024) void k_scan(const int* __restrict__ counts, int* __restrict__ starts,
                       int* __restrict__ cursor, int N, int Etot){
  __shared__ int s[1024];
  int t = threadIdx.x;
  const int CHN = (N + 1023) / 1024;
  int lo = t*CHN, hi = min(lo+CHN, N);
  int loc = 0;
  for (int i = lo; i < hi; i++) loc += counts[i];
  s[t] = loc;
  __syncthreads();
  for (int off = 1; off < 1024; off <<= 1){
    int v = (t >= off) ? s[t-off] : 0;
    __syncthreads();
    s[t] += v;
    __syncthreads();
  }
  int run = (t == 0) ? 0 : s[t-1];
  for (int i = lo; i < hi; i++){
    starts[i] = run; cursor[i] = run; run += counts[i];
  }
  if (t == 0) starts[N] = Etot;
}

// scatter: 4B payload (CSR position -> original edge id)
__global__ void k_scatter(const int* __restrict__ dst, int* __restrict__ cursor,
                          int* __restrict__ eids, int E, int Etot){
  int e = blockIdx.x*256 + threadIdx.x;
  if (e >= Etot) return;
  int dn = (e < E) ? dst[e] : (e - E);
  int pos = atomicAdd(&cursor[dn], 1);
  eids[pos] = e;
}

// ---- degree-sorted node permutation (LPT: descending degree) ----
__global__ void k_dhist(const int* __restrict__ starts, int* __restrict__ dhist, int N){
  int n = blockIdx.x*256 + threadIdx.x;
  if (n >= N) return;
  int d = min(starts[n+1] - starts[n], DBINS-1);
  atomicAdd(&dhist[d], 1);
}
__global__ __launch_bounds__(1024) void k_dscan(const int* __restrict__ dhist, int* __restrict__ dcur){
  __shared__ int s[DBINS];
  int t = threadIdx.x;
  // descending: dcur[d] = sum of dhist[d'] for d' > d
  s[t] = dhist[DBINS-1-t];   // s[i] = hist of degree (DBINS-1-i)
  __syncthreads();
  for (int off = 1; off < DBINS; off <<= 1){
    int v = (t >= off) ? s[t-off] : 0;
    __syncthreads();
    s[t] += v;
    __syncthreads();
  }
  // exclusive prefix in reversed order
  int incl = s[t];
  int excl = incl - dhist[DBINS-1-t];
  dcur[DBINS-1-t] = excl;
}
__global__ void k_dscatter(const int* __restrict__ starts, int* __restrict__ dcur,
                           int* __restrict__ perm, int N){
  int n = blockIdx.x*256 + threadIdx.x;
  if (n >= N) return;
  int d = min(starts[n+1] - starts[n], DBINS-1);
  int pos = atomicAdd(&dcur[d], 1);
  perm[pos] = n;
}

// build srcC, fp16 attr, and per-layer attrdot in CSR order (fused)
__global__ void k_gather_csr(const int* __restrict__ eids, const int* __restrict__ src,
                             const float* __restrict__ eattr, const float* __restrict__ c5,
                             int* __restrict__ srcC, __half* __restrict__ attrC16,
                             float* __restrict__ attrdot, int E, int Etot){
  int i = blockIdx.x*256 + threadIdx.x;
  if (i >= Etot) return;
  int eid = eids[i];
  float a[FF];
  if (eid < E){
    srcC[i] = src[eid];
    const float4* in = (const float4*)&eattr[(size_t)eid*FF];
    float4 q0=in[0], q1=in[1], q2=in[2], q3=in[3];
    a[0]=q0.x; a[1]=q0.y; a[2]=q0.z; a[3]=q0.w;
    a[4]=q1.x; a[5]=q1.y; a[6]=q1.z; a[7]=q1.w;
    a[8]=q2.x; a[9]=q2.y; a[10]=q2.z; a[11]=q2.w;
    a[12]=q3.x; a[13]=q3.y; a[14]=q3.z; a[15]=q3.w;
  } else {
    srcC[i] = eid - E;
    #pragma unroll
    for (int f = 0; f < FF; f++) a[f] = 0.f;
  }
  uint4 pk0, pk1;
  {
    __half2 h0 = __floats2half2_rn(a[0],a[1]),  h1 = __floats2half2_rn(a[2],a[3]);
    __half2 h2 = __floats2half2_rn(a[4],a[5]),  h3 = __floats2half2_rn(a[6],a[7]);
    __half2 h4 = __floats2half2_rn(a[8],a[9]),  h5 = __floats2half2_rn(a[10],a[11]);
    __half2 h6 = __floats2half2_rn(a[12],a[13]),h7 = __floats2half2_rn(a[14],a[15]);
    pk0.x=*(unsigned*)&h0; pk0.y=*(unsigned*)&h1; pk0.z=*(unsigned*)&h2; pk0.w=*(unsigned*)&h3;
    pk1.x=*(unsigned*)&h4; pk1.y=*(unsigned*)&h5; pk1.z=*(unsigned*)&h6; pk1.w=*(unsigned*)&h7;
  }
  uint4* ob = (uint4*)&attrC16[(size_t)i*FF];
  ob[0] = pk0; ob[1] = pk1;
  #pragma unroll
  for (int l = 0; l < 5; l++){
    const float* cl = c5 + (size_t)l*34;
    float d0 = 0.f, d1 = 0.f;
    #pragma unroll
    for (int f = 0; f < FF; f++){
      d0 = fmaf(a[f], cl[f], d0);
      d1 = fmaf(a[f], cl[FF+f], d1);
    }
    *(float2*)&attrdot[((size_t)l*Etot + i)*2] = make_float2(d0, d1);
  }
}

// xw8[N,256] (fp8 e4m3) = h[N,128] @ Wh[128,256](fp16); fused s[n][4] (from fp32 acc)
__global__ __launch_bounds__(256) void k_gemm_xw(const float* __restrict__ h, const __half* __restrict__ Wh,
                         const float* __restrict__ att, unsigned char* __restrict__ xw8,
                         float* __restrict__ sbuf, int N){
  __shared__ float sx[16][DD];
  int r0 = blockIdx.x * 16;
  int rows = min(16, N - r0);
  int t = threadIdx.x;
  for (int idx = t; idx < 16*(DD/4); idx += 256){
    int r = idx >> 5, kq = idx & 31;
    float4 v = make_float4(0.f,0.f,0.f,0.f);
    if (r < rows) v = *(const float4*)&h[(size_t)(r0+r)*DD + kq*4];
    *(float4*)&sx[r][kq*4] = v;
  }
  __syncthreads();
  int tx = t & 63, ty = t >> 6;
  int c0 = tx*4;
  float4 acc[4];
  #pragma unroll
  for (int r = 0; r < 4; r++) acc[r] = make_float4(0.f,0.f,0.f,0.f);
  #pragma unroll 4
  for (int kq = 0; kq < 32; kq++){
    float4 w0 = h4f(*(const uint2*)&Wh[(size_t)(kq*4+0)*HD + c0]);
    float4 w1 = h4f(*(const uint2*)&Wh[(size_t)(kq*4+1)*HD + c0]);
    float4 w2 = h4f(*(const uint2*)&Wh[(size_t)(kq*4+2)*HD + c0]);
    float4 w3 = h4f(*(const uint2*)&Wh[(size_t)(kq*4+3)*HD + c0]);
    #pragma unroll
    for (int r = 0; r < 4; r++){
      float4 hv = *(const float4*)&sx[ty*4+r][kq*4];
      acc[r].x = fmaf(hv.x, w0.x, acc[r].x); acc[r].y = fmaf(hv.x, w0.y, acc[r].y);
      acc[r].z = fmaf(hv.x, w0.z, acc[r].z); acc[r].w = fmaf(hv.x, w0.w, acc[r].w);
      acc[r].x = fmaf(hv.y, w1.x, acc[r].x); acc[r].y = fmaf(hv.y, w1.y, acc[r].y);
      acc[r].z = fmaf(hv.y, w1.z, acc[r].z); acc[r].w = fmaf(hv.y, w1.w, acc[r].w);
      acc[r].x = fmaf(hv.z, w2.x, acc[r].x); acc[r].y = fmaf(hv.z, w2.y, acc[r].y);
      acc[r].z = fmaf(hv.z, w2.z, acc[r].z); acc[r].w = fmaf(hv.z, w2.w, acc[r].w);
      acc[r].x = fmaf(hv.w, w3.x, acc[r].x); acc[r].y = fmaf(hv.w, w3.y, acc[r].y);
      acc[r].z = fmaf(hv.w, w3.z, acc[r].z); acc[r].w = fmaf(hv.w, w3.w, acc[r].w);
    }
  }
  #pragma unroll
  for (int r = 0; r < 4; r++){
    if (ty*4+r < rows){
      __hip_fp8_e4m3 q0(acc[r].x), q1(acc[r].y), q2(acc[r].z), q3(acc[r].w);
      unsigned pk = (unsigned)q0.__x | ((unsigned)q1.__x << 8)
                  | ((unsigned)q2.__x << 16) | ((unsigned)q3.__x << 24);
      *(unsigned*)&xw8[(size_t)(r0+ty*4+r)*HD + c0] = pk;
    }
  }
  int hsel = tx >> 5;
  int cm = c0 & 127;
  float4 ai = *(const float4*)&att[hsel*2*DD + cm];
  float4 aj = *(const float4*)&att[hsel*2*DD + DD + cm];
  #pragma unroll
  for (int r = 0; r < 4; r++){
    float pi = acc[r].x*ai.x + acc[r].y*ai.y + acc[r].z*ai.z + acc[r].w*ai.w;
    float pj = acc[r].x*aj.x + acc[r].y*aj.y + acc[r].z*aj.z + acc[r].w*aj.w;
    #pragma unroll
    for (int off = 16; off; off >>= 1){
      pi += __shfl_xor(pi, off);
      pj += __shfl_xor(pj, off);
    }
    int row = ty*4 + r;
    if ((tx & 31) == 0 && row < rows){
      sbuf[(size_t)(r0+row)*4 + 0 + hsel] = pi;
      sbuf[(size_t)(r0+row)*4 + 2 + hsel] = pj;
    }
  }
}

// Wave-per-node single pass, R18 body, node id via degree-sorted perm (LPT packing:
// blocks get 4 equal-degree nodes, heaviest first -> no convoy, small tail).
__global__ __launch_bounds__(256) void k_aggr(const int* __restrict__ perm,
                      const int* __restrict__ starts, const int* __restrict__ srcC,
                      const __half* __restrict__ attrC16, const float* __restrict__ adL,
                      const float* __restrict__ s, const float* __restrict__ c,
                      const unsigned char* __restrict__ xw8, const float* __restrict__ ew,
                      const float* __restrict__ eb, const float* __restrict__ bias,
                      float* __restrict__ out, int N, int relu){
  int lane = threadIdx.x & 63, wid = threadIdx.x >> 6;
  int ni = blockIdx.x*4 + wid;
  if (ni >= N) return;
  int n = perm[ni];

  float c32 = c[32], c33 = c[33];
  float sdx = s[(size_t)n*4+0], sdy = s[(size_t)n*4+1];
  int st = starts[n];
  int deg = starts[n+1] - st;

  int f2 = lane & 15;
  int h2 = (lane >> 4) & 1;
  int hq = lane >> 5;
  const unsigned char* xbase = xw8 + lane*4;   // lane's 4-column slice (4B)

  float aAx=0.f, aAy=0.f, aAz=0.f, aAw=0.f;
  float aBx=0.f, aBy=0.f, aBz=0.f, aBw=0.f;
  float ls0=0.f, ls1=0.f, taccA=0.f, taccB=0.f;

  for (int base = 0; base < deg; base += 64){
    int cnt = min(64, deg - base);
    float e0 = 0.f, e1 = 0.f; int msrc = 0;
    if (lane < cnt){
      int idx = st + base + lane;
      msrc = srcC[idx];
      float2 sj = *(const float2*)&s[(size_t)msrc*4+2];
      float2 ad = *(const float2*)&adL[(size_t)idx*2];
      float x0 = sdx + sj.x + c32 + ad.x;
      float x1 = sdy + sj.y + c33 + ad.y;
      x0 = (x0 > 0.f) ? x0 : NEG_SLOPE*x0;
      x1 = (x1 > 0.f) ? x1 : NEG_SLOPE*x1;
      e0 = expf(x0); e1 = expf(x1);
      ls0 += e0; ls1 += e1;
    }
    const __half* abase = &attrC16[(size_t)(st+base)*FF + f2];
    int i = 0;
    for (; i + BB <= cnt; i += BB){
      // phase 1: issue all independent gathers + attr reads
      unsigned u[BB];
      float av[BB];
      #pragma unroll
      for (int k = 0; k < BB; k++){
        int sn = rdlanei(msrc, i+k);
        u[k] = *(const unsigned*)(xbase + (size_t)sn*HD);
      }
      #pragma unroll
      for (int k = 0; k < BB; k++) av[k] = __half2float(abase[(size_t)(i+k)*FF]);
      // phase 2: consume
      #pragma unroll
      for (int k = 0; k < BB; k++){
        float w0 = rdlanef(e0, i+k);
        float w1 = rdlanef(e1, i+k);
        float ws = hq ? w1 : w0;
        float wt = h2 ? w1 : w0;
        float4 xv = fp8x4_to_f4(u[k]);
        if (k & 1){
          aBx = fmaf(ws, xv.x, aBx); aBy = fmaf(ws, xv.y, aBy);
          aBz = fmaf(ws, xv.z, aBz); aBw = fmaf(ws, xv.w, aBw);
          taccB = fmaf(wt, av[k], taccB);
        } else {
          aAx = fmaf(ws, xv.x, aAx); aAy = fmaf(ws, xv.y, aAy);
          aAz = fmaf(ws, xv.z, aAz); aAw = fmaf(ws, xv.w, aAw);
          taccA = fmaf(wt, av[k], taccA);
        }
      }
    }
    for (; i < cnt; i++){
      int sn = rdlanei(msrc, i);
      float w0 = rdlanef(e0, i);
      float w1 = rdlanef(e1, i);
      unsigned u0 = *(const unsigned*)(xbase + (size_t)sn*HD);
      float av0 = __half2float(abase[(size_t)i*FF]);
      float ws = hq ? w1 : w0;
      float wt = h2 ? w1 : w0;
      float4 xv = fp8x4_to_f4(u0);
      aAx = fmaf(ws, xv.x, aAx); aAy = fmaf(ws, xv.y, aAy);
      aAz = fmaf(ws, xv.z, aAz); aAw = fmaf(ws, xv.w, aAw);
      taccA = fmaf(wt, av0, taccA);
    }
  }
  float ax = aAx + aBx, ay = aAy + aBy, az = aAz + aBz, aw = aAw + aBw;
  float tacc = taccA + taccB;
  #pragma unroll
  for (int off = 32; off; off >>= 1){
    ls0 += __shfl_xor(ls0, off);
    ls1 += __shfl_xor(ls1, off);
  }
  // every lane accumulated tacc over ALL edges: lane (hq*16+f) holds complete t[h][f]

  // epilogue: factored edge-emb + normalize + head-mean + bias
  int c0 = lane*4;
  float th[FF];
  #pragma unroll
  for (int f = 0; f < FF; f++) th[f] = __shfl(tacc, hq*FF + f);
  float embq[4];
  #pragma unroll
  for (int q = 0; q < 4; q++){
    const float4* er = (const float4*)&ew[(size_t)(c0+q)*FF];
    float4 g0 = er[0], g1 = er[1], g2 = er[2], g3 = er[3];
    float v = th[0]*g0.x + th[1]*g0.y + th[2]*g0.z + th[3]*g0.w;
    v = fmaf(th[4],  g1.x, v); v = fmaf(th[5],  g1.y, v); v = fmaf(th[6],  g1.z, v); v = fmaf(th[7],  g1.w, v);
    v = fmaf(th[8],  g2.x, v); v = fmaf(th[9],  g2.y, v); v = fmaf(th[10], g2.z, v); v = fmaf(th[11], g2.w, v);
    v = fmaf(th[12], g3.x, v); v = fmaf(th[13], g3.y, v); v = fmaf(th[14], g3.z, v); v = fmaf(th[15], g3.w, v);
    embq[q] = v;
  }
  float di = 1.f/((hq ? ls1 : ls0) + EPSV);
  float4 ebv = *(const float4*)&eb[c0];
  float r0 = di*(ax + embq[0]) + ebv.x;
  float r1 = di*(ay + embq[1]) + ebv.y;
  float r2 = di*(az + embq[2]) + ebv.z;
  float r3 = di*(aw + embq[3]) + ebv.w;
  float p0 = __shfl_xor(r0, 32);
  float p1 = __shfl_xor(r1, 32);
  float p2 = __shfl_xor(r2, 32);
  float p3 = __shfl_xor(r3, 32);
  if (lane < 32){
    float4 bv = *(const float4*)&bias[c0];
    float4 v;
    v.x = 0.5f*(r0 + p0) + bv.x;
    v.y = 0.5f*(r1 + p1) + bv.y;
    v.z = 0.5f*(r2 + p2) + bv.z;
    v.w = 0.5f*(r3 + p3) + bv.w;
    if (relu){
      v.x = fmaxf(v.x, 0.f); v.y = fmaxf(v.y, 0.f);
      v.z = fmaxf(v.z, 0.f); v.w = fmaxf(v.w, 0.f);
    }
    *(float4*)&out[(size_t)n*DD + c0] = v;
  }
}

extern "C" void kernel_launch(void* const* d_in, const int* in_sizes, int n_in,
                              void* d_out, int out_size, void* d_ws, size_t ws_size,
                              hipStream_t stream){
  const float* x       = (const float*)d_in[0];
  const int*   eidx    = (const int*)d_in[1];
  const float* eattr   = (const float*)d_in[2];
  const float* weights = (const float*)d_in[3];
  const float* atts    = (const float*)d_in[4];
  const float* biases  = (const float*)d_in[5];
  const float* edge_ws = (const float*)d_in[6];
  const float* edge_bs = (const float*)d_in[7];
  const int N = in_sizes[0]/DD;
  const int E = in_sizes[1]/2;
  const int Etot = E + N;
  const int* src = eidx;
  const int* dst = eidx + E;

  char* p = (char*)d_ws;
  auto alloc = [&](size_t bytes){ void* r = (void*)p; p += (bytes + 255) & ~(size_t)255; return r; };
  float*         hA      = (float*)alloc((size_t)N*DD*4);
  float*         hB      = (float*)alloc((size_t)N*DD*4);
  unsigned char* xw8     = (unsigned char*)alloc((size_t)N*HD);
  float*         sbuf    = (float*)alloc((size_t)N*4*4);      // aliases counts/cursor during build
  int*           starts  = (int*)alloc((size_t)(N+1)*4);
  int*           srcC    = (int*)alloc((size_t)Etot*4);
  int*           eids    = (int*)alloc((size_t)Etot*4);
  __half*        attrC16 = (__half*)alloc((size_t)Etot*FF*2);
  float*         attrdot = (float*)alloc((size_t)5*Etot*2*4);
  __half*        wh      = (__half*)alloc((size_t)5*DD*HD*2);
  float*         c5      = (float*)alloc(5*34*4);
  int*           perm    = (int*)alloc((size_t)N*4);
  int*           dhist   = (int*)alloc((size_t)DBINS*4);
  int*           dcur    = (int*)alloc((size_t)DBINS*4);

  int* counts = (int*)sbuf;                       // build-phase alias
  int* cursor = (int*)((char*)sbuf + 65536);      // build-phase alias

  const int ebl = (Etot + 255)/256;
  const int nbl = (N + 255)/256;

  // CSR build (layer-invariant) + constants + W fp16 + attr precompute
  (void)hipMemsetAsync(counts, 0, (size_t)N*4, stream);
  (void)hipMemsetAsync(dhist, 0, (size_t)DBINS*4, stream);
  k_hist_prec<<<ebl+165, 256, 0, stream>>>(dst, counts, atts, edge_ws, edge_bs, weights,
                                           c5, wh, E, Etot, ebl);
  k_scan<<<1, 1024, 0, stream>>>(counts, starts, cursor, N, Etot);
  k_scatter<<<ebl, 256, 0, stream>>>(dst, cursor, eids, E, Etot);
  // degree-sorted node permutation (descending)
  k_dhist<<<nbl, 256, 0, stream>>>(starts, dhist, N);
  k_dscan<<<1, DBINS, 0, stream>>>(dhist, dcur);
  k_dscatter<<<nbl, 256, 0, stream>>>(starts, dcur, perm, N);
  k_gather_csr<<<ebl, 256, 0, stream>>>(eids, src, eattr, c5, srcC, attrC16, attrdot, E, Etot);

  const float* hin = x;
  for (int l = 0; l < 5; l++){
    const __half* Whl = wh + (size_t)l*DD*HD;
    const float* att = atts    + (size_t)l*HEADS*2*DD;
    const float* b   = biases  + (size_t)l*DD;
    const float* ew  = edge_ws + (size_t)l*HD*FF;
    const float* eb  = edge_bs + (size_t)l*HD;
    const float* c   = c5 + (size_t)l*34;
    const float* adL = attrdot + (size_t)l*Etot*2;
    float* hout = (l == 4) ? (float*)d_out : ((l & 1) ? hB : hA);
    int relu = (l < 4) ? 1 : 0;

    k_gemm_xw<<<(N+15)/16, 256, 0, stream>>>(hin, Whl, att, xw8, sbuf, N);
    k_aggr<<<(N+3)/4, 256, 0, stream>>>(perm, starts, srcC, attrC16, adL, sbuf, c, xw8, ew, eb, b, hout, N, relu);

    hin = hout;
  }
}

// Round 22
// 341.976 us; speedup vs baseline: 1.1727x; 1.1727x over previous
//
#include <hip/hip_runtime.h>
#include <hip/hip_fp16.h>
#include <hip/hip_fp8.h>

#define HEADS 2
#define DD 128
#define FF 16
#define HD 256  // HEADS*DD
#define NEG_SLOPE 0.2f
#define EPSV 1e-16f
#define BB 8

typedef float v2f __attribute__((ext_vector_type(2)));

static __device__ __forceinline__ float rdlanef(float v, int i){
  return __uint_as_float(__builtin_amdgcn_readlane(__float_as_uint(v), i));
}
static __device__ __forceinline__ int rdlanei(int v, int i){
  return __builtin_amdgcn_readlane(v, i);
}
static __device__ __forceinline__ float4 h4f(uint2 u){
  float2 f0 = __half22float2(*(__half2*)&u.x);
  float2 f1 = __half22float2(*(__half2*)&u.y);
  return make_float4(f0.x, f0.y, f1.x, f1.y);
}
static __device__ __forceinline__ float4 fp8x4_to_f4(unsigned u){
#if __has_builtin(__builtin_amdgcn_cvt_pk_f32_fp8)
  v2f lo = __builtin_amdgcn_cvt_pk_f32_fp8(u, false);   // bytes 0,1
  v2f hi = __builtin_amdgcn_cvt_pk_f32_fp8(u, true);    // bytes 2,3
  return make_float4(lo.x, lo.y, hi.x, hi.y);
#else
  __hip_fp8_e4m3 b0, b1, b2, b3;
  b0.__x = (unsigned char)(u & 0xff);
  b1.__x = (unsigned char)((u >> 8) & 0xff);
  b2.__x = (unsigned char)((u >> 16) & 0xff);
  b3.__x = (unsigned char)((u >> 24) & 0xff);
  return make_float4((float)b0, (float)b1, (float)b2, (float)b3);
#endif
}

// ---------------- CSR build ----------------
// blocks [0,ebl): dst histogram. [ebl,ebl+5): c5 constants. [ebl+5,ebl+165): W->fp16.
__global__ void k_hist_prec(const int* __restrict__ dst, int* __restrict__ counts,
                            const float* __restrict__ atts, const float* __restrict__ edge_ws,
                            const float* __restrict__ edge_bs, const float* __restrict__ weights,
                            float* __restrict__ c5, __half* __restrict__ wh,
                            int E, int Etot, int ebl){
  int bid = blockIdx.x;
  if (bid >= ebl){
    int k = bid - ebl;
    if (k < 5){
      int l = k, t = threadIdx.x;
      const float* att = atts    + (size_t)l*HEADS*2*DD;
      const float* ew  = edge_ws + (size_t)l*HD*FF;
      const float* eb  = edge_bs + (size_t)l*HD;
      float* c = c5 + (size_t)l*34;
      if (t < 32){
        int h = t >> 4, f = t & 15;
        float acc = 0.f;
        for (int d = 0; d < DD; d++) acc += att[h*2*DD + DD + d]*ew[(size_t)(h*DD+d)*FF + f];
        c[h*FF + f] = acc;
      } else if (t < 34){
        int h = t - 32;
        float acc = 0.f;
        for (int d = 0; d < DD; d++) acc += att[h*2*DD + DD + d]*eb[h*DD + d];
        c[32 + h] = acc;
      }
    } else {
      int base = (k - 5)*1024 + threadIdx.x*4;   // 5*DD*HD = 163840 = 160*1024
      float4 w = *(const float4*)&weights[base];
      __half2 p0 = __floats2half2_rn(w.x, w.y);
      __half2 p1 = __floats2half2_rn(w.z, w.w);
      uint2 pk; pk.x = *(unsigned*)&p0; pk.y = *(unsigned*)&p1;
      *(uint2*)&wh[base] = pk;
    }
    return;
  }
  int e = bid*256 + threadIdx.x;
  if (e >= Etot) return;
  int dn = (e < E) ? dst[e] : (e - E);
  atomicAdd(&counts[dn], 1);
}

__global__ __launch_bounds__(1024) void k_scan(const int* __restrict__ counts, int* __restrict__ starts,
                       int* __restrict__ cursor, int N, int Etot){
  __shared__ int s[1024];
  int t = threadIdx.x;
  const int CHN = (N + 1023) / 1024;
  int lo = t*CHN, hi = min(lo+CHN, N);
  int loc = 0;
  for (int i = lo; i < hi; i++) loc += counts[i];
  s[t] = loc;
  __syncthreads();
  for (int off = 1; off < 1024; off <<= 1){
    int v = (t >= off) ? s[t-off] : 0;
    __syncthreads();
    s[t] += v;
    __syncthreads();
  }
  int run = (t == 0) ? 0 : s[t-1];
  for (int i = lo; i < hi; i++){
    starts[i] = run; cursor[i] = run; run += counts[i];
  }
  if (t == 0) starts[N] = Etot;
}

// scatter: 4B payload (CSR position -> original edge id)
__global__ void k_scatter(const int* __restrict__ dst, int* __restrict__ cursor,
                          int* __restrict__ eids, int E, int Etot){
  int e = blockIdx.x*256 + threadIdx.x;
  if (e >= Etot) return;
  int dn = (e < E) ? dst[e] : (e - E);
  int pos = atomicAdd(&cursor[dn], 1);
  eids[pos] = e;
}

// build srcC, fp16 attr, and per-layer attrdot in CSR order (fused)
__global__ void k_gather_csr(const int* __restrict__ eids, const int* __restrict__ src,
                             const float* __restrict__ eattr, const float* __restrict__ c5,
                             int* __restrict__ srcC, __half* __restrict__ attrC16,
                             float* __restrict__ attrdot, int E, int Etot){
  int i = blockIdx.x*256 + threadIdx.x;
  if (i >= Etot) return;
  int eid = eids[i];
  float a[FF];
  if (eid < E){
    srcC[i] = src[eid];
    const float4* in = (const float4*)&eattr[(size_t)eid*FF];
    float4 q0=in[0], q1=in[1], q2=in[2], q3=in[3];
    a[0]=q0.x; a[1]=q0.y; a[2]=q0.z; a[3]=q0.w;
    a[4]=q1.x; a[5]=q1.y; a[6]=q1.z; a[7]=q1.w;
    a[8]=q2.x; a[9]=q2.y; a[10]=q2.z; a[11]=q2.w;
    a[12]=q3.x; a[13]=q3.y; a[14]=q3.z; a[15]=q3.w;
  } else {
    srcC[i] = eid - E;
    #pragma unroll
    for (int f = 0; f < FF; f++) a[f] = 0.f;
  }
  uint4 pk0, pk1;
  {
    __half2 h0 = __floats2half2_rn(a[0],a[1]),  h1 = __floats2half2_rn(a[2],a[3]);
    __half2 h2 = __floats2half2_rn(a[4],a[5]),  h3 = __floats2half2_rn(a[6],a[7]);
    __half2 h4 = __floats2half2_rn(a[8],a[9]),  h5 = __floats2half2_rn(a[10],a[11]);
    __half2 h6 = __floats2half2_rn(a[12],a[13]),h7 = __floats2half2_rn(a[14],a[15]);
    pk0.x=*(unsigned*)&h0; pk0.y=*(unsigned*)&h1; pk0.z=*(unsigned*)&h2; pk0.w=*(unsigned*)&h3;
    pk1.x=*(unsigned*)&h4; pk1.y=*(unsigned*)&h5; pk1.z=*(unsigned*)&h6; pk1.w=*(unsigned*)&h7;
  }
  uint4* ob = (uint4*)&attrC16[(size_t)i*FF];
  ob[0] = pk0; ob[1] = pk1;
  #pragma unroll
  for (int l = 0; l < 5; l++){
    const float* cl = c5 + (size_t)l*34;
    float d0 = 0.f, d1 = 0.f;
    #pragma unroll
    for (int f = 0; f < FF; f++){
      d0 = fmaf(a[f], cl[f], d0);
      d1 = fmaf(a[f], cl[FF+f], d1);
    }
    *(float2*)&attrdot[((size_t)l*Etot + i)*2] = make_float2(d0, d1);
  }
}

// xw8[N,256] (fp8 e4m3) = h[N,128] @ Wh[128,256](fp16); fused s[n][4] (from fp32 acc)
__global__ __launch_bounds__(256) void k_gemm_xw(const float* __restrict__ h, const __half* __restrict__ Wh,
                         const float* __restrict__ att, unsigned char* __restrict__ xw8,
                         float* __restrict__ sbuf, int N){
  __shared__ float sx[16][DD];
  int r0 = blockIdx.x * 16;
  int rows = min(16, N - r0);
  int t = threadIdx.x;
  for (int idx = t; idx < 16*(DD/4); idx += 256){
    int r = idx >> 5, kq = idx & 31;
    float4 v = make_float4(0.f,0.f,0.f,0.f);
    if (r < rows) v = *(const float4*)&h[(size_t)(r0+r)*DD + kq*4];
    *(float4*)&sx[r][kq*4] = v;
  }
  __syncthreads();
  int tx = t & 63, ty = t >> 6;
  int c0 = tx*4;
  float4 acc[4];
  #pragma unroll
  for (int r = 0; r < 4; r++) acc[r] = make_float4(0.f,0.f,0.f,0.f);
  #pragma unroll 4
  for (int kq = 0; kq < 32; kq++){
    float4 w0 = h4f(*(const uint2*)&Wh[(size_t)(kq*4+0)*HD + c0]);
    float4 w1 = h4f(*(const uint2*)&Wh[(size_t)(kq*4+1)*HD + c0]);
    float4 w2 = h4f(*(const uint2*)&Wh[(size_t)(kq*4+2)*HD + c0]);
    float4 w3 = h4f(*(const uint2*)&Wh[(size_t)(kq*4+3)*HD + c0]);
    #pragma unroll
    for (int r = 0; r < 4; r++){
      float4 hv = *(const float4*)&sx[ty*4+r][kq*4];
      acc[r].x = fmaf(hv.x, w0.x, acc[r].x); acc[r].y = fmaf(hv.x, w0.y, acc[r].y);
      acc[r].z = fmaf(hv.x, w0.z, acc[r].z); acc[r].w = fmaf(hv.x, w0.w, acc[r].w);
      acc[r].x = fmaf(hv.y, w1.x, acc[r].x); acc[r].y = fmaf(hv.y, w1.y, acc[r].y);
      acc[r].z = fmaf(hv.y, w1.z, acc[r].z); acc[r].w = fmaf(hv.y, w1.w, acc[r].w);
      acc[r].x = fmaf(hv.z, w2.x, acc[r].x); acc[r].y = fmaf(hv.z, w2.y, acc[r].y);
      acc[r].z = fmaf(hv.z, w2.z, acc[r].z); acc[r].w = fmaf(hv.z, w2.w, acc[r].w);
      acc[r].x = fmaf(hv.w, w3.x, acc[r].x); acc[r].y = fmaf(hv.w, w3.y, acc[r].y);
      acc[r].z = fmaf(hv.w, w3.z, acc[r].z); acc[r].w = fmaf(hv.w, w3.w, acc[r].w);
    }
  }
  #pragma unroll
  for (int r = 0; r < 4; r++){
    if (ty*4+r < rows){
      __hip_fp8_e4m3 q0(acc[r].x), q1(acc[r].y), q2(acc[r].z), q3(acc[r].w);
      unsigned pk = (unsigned)q0.__x | ((unsigned)q1.__x << 8)
                  | ((unsigned)q2.__x << 16) | ((unsigned)q3.__x << 24);
      *(unsigned*)&xw8[(size_t)(r0+ty*4+r)*HD + c0] = pk;
    }
  }
  int hsel = tx >> 5;
  int cm = c0 & 127;
  float4 ai = *(const float4*)&att[hsel*2*DD + cm];
  float4 aj = *(const float4*)&att[hsel*2*DD + DD + cm];
  #pragma unroll
  for (int r = 0; r < 4; r++){
    float pi = acc[r].x*ai.x + acc[r].y*ai.y + acc[r].z*ai.z + acc[r].w*ai.w;
    float pj = acc[r].x*aj.x + acc[r].y*aj.y + acc[r].z*aj.z + acc[r].w*aj.w;
    #pragma unroll
    for (int off = 16; off; off >>= 1){
      pi += __shfl_xor(pi, off);
      pj += __shfl_xor(pj, off);
    }
    int row = ty*4 + r;
    if ((tx & 31) == 0 && row < rows){
      sbuf[(size_t)(r0+row)*4 + 0 + hsel] = pi;
      sbuf[(size_t)(r0+row)*4 + 2 + hsel] = pj;
    }
  }
}

// Wave-per-node single pass, flat 8-deep batched fp8 gathers + packed cvt (R18 = best).
__global__ __launch_bounds__(256) void k_aggr(const int* __restrict__ starts, const int* __restrict__ srcC,
                      const __half* __restrict__ attrC16, const float* __restrict__ adL,
                      const float* __restrict__ s, const float* __restrict__ c,
                      const unsigned char* __restrict__ xw8, const float* __restrict__ ew,
                      const float* __restrict__ eb, const float* __restrict__ bias,
                      float* __restrict__ out, int N, int relu){
  int lane = threadIdx.x & 63, wid = threadIdx.x >> 6;
  int n = blockIdx.x*4 + wid;
  if (n >= N) return;

  float c32 = c[32], c33 = c[33];
  float sdx = s[(size_t)n*4+0], sdy = s[(size_t)n*4+1];
  int st = starts[n];
  int deg = starts[n+1] - st;

  int f2 = lane & 15;
  int h2 = (lane >> 4) & 1;
  int hq = lane >> 5;
  const unsigned char* xbase = xw8 + lane*4;   // lane's 4-column slice (4B)

  float aAx=0.f, aAy=0.f, aAz=0.f, aAw=0.f;
  float aBx=0.f, aBy=0.f, aBz=0.f, aBw=0.f;
  float ls0=0.f, ls1=0.f, taccA=0.f, taccB=0.f;

  for (int base = 0; base < deg; base += 64){
    int cnt = min(64, deg - base);
    float e0 = 0.f, e1 = 0.f; int msrc = 0;
    if (lane < cnt){
      int idx = st + base + lane;
      msrc = srcC[idx];
      float2 sj = *(const float2*)&s[(size_t)msrc*4+2];
      float2 ad = *(const float2*)&adL[(size_t)idx*2];
      float x0 = sdx + sj.x + c32 + ad.x;
      float x1 = sdy + sj.y + c33 + ad.y;
      x0 = (x0 > 0.f) ? x0 : NEG_SLOPE*x0;
      x1 = (x1 > 0.f) ? x1 : NEG_SLOPE*x1;
      e0 = expf(x0); e1 = expf(x1);
      ls0 += e0; ls1 += e1;
    }
    const __half* abase = &attrC16[(size_t)(st+base)*FF + f2];
    int i = 0;
    for (; i + BB <= cnt; i += BB){
      // phase 1: issue all independent gathers + attr reads
      unsigned u[BB];
      float av[BB];
      #pragma unroll
      for (int k = 0; k < BB; k++){
        int sn = rdlanei(msrc, i+k);
        u[k] = *(const unsigned*)(xbase + (size_t)sn*HD);
      }
      #pragma unroll
      for (int k = 0; k < BB; k++) av[k] = __half2float(abase[(size_t)(i+k)*FF]);
      // phase 2: consume
      #pragma unroll
      for (int k = 0; k < BB; k++){
        float w0 = rdlanef(e0, i+k);
        float w1 = rdlanef(e1, i+k);
        float ws = hq ? w1 : w0;
        float wt = h2 ? w1 : w0;
        float4 xv = fp8x4_to_f4(u[k]);
        if (k & 1){
          aBx = fmaf(ws, xv.x, aBx); aBy = fmaf(ws, xv.y, aBy);
          aBz = fmaf(ws, xv.z, aBz); aBw = fmaf(ws, xv.w, aBw);
          taccB = fmaf(wt, av[k], taccB);
        } else {
          aAx = fmaf(ws, xv.x, aAx); aAy = fmaf(ws, xv.y, aAy);
          aAz = fmaf(ws, xv.z, aAz); aAw = fmaf(ws, xv.w, aAw);
          taccA = fmaf(wt, av[k], taccA);
        }
      }
    }
    for (; i < cnt; i++){
      int sn = rdlanei(msrc, i);
      float w0 = rdlanef(e0, i);
      float w1 = rdlanef(e1, i);
      unsigned u0 = *(const unsigned*)(xbase + (size_t)sn*HD);
      float av0 = __half2float(abase[(size_t)i*FF]);
      float ws = hq ? w1 : w0;
      float wt = h2 ? w1 : w0;
      float4 xv = fp8x4_to_f4(u0);
      aAx = fmaf(ws, xv.x, aAx); aAy = fmaf(ws, xv.y, aAy);
      aAz = fmaf(ws, xv.z, aAz); aAw = fmaf(ws, xv.w, aAw);
      taccA = fmaf(wt, av0, taccA);
    }
  }
  float ax = aAx + aBx, ay = aAy + aBy, az = aAz + aBz, aw = aAw + aBw;
  float tacc = taccA + taccB;
  #pragma unroll
  for (int off = 32; off; off >>= 1){
    ls0 += __shfl_xor(ls0, off);
    ls1 += __shfl_xor(ls1, off);
  }
  // every lane accumulated tacc over ALL edges: lane (hq*16+f) holds complete t[h][f]

  // epilogue: factored edge-emb + normalize + head-mean + bias
  int c0 = lane*4;
  float th[FF];
  #pragma unroll
  for (int f = 0; f < FF; f++) th[f] = __shfl(tacc, hq*FF + f);
  float embq[4];
  #pragma unroll
  for (int q = 0; q < 4; q++){
    const float4* er = (const float4*)&ew[(size_t)(c0+q)*FF];
    float4 g0 = er[0], g1 = er[1], g2 = er[2], g3 = er[3];
    float v = th[0]*g0.x + th[1]*g0.y + th[2]*g0.z + th[3]*g0.w;
    v = fmaf(th[4],  g1.x, v); v = fmaf(th[5],  g1.y, v); v = fmaf(th[6],  g1.z, v); v = fmaf(th[7],  g1.w, v);
    v = fmaf(th[8],  g2.x, v); v = fmaf(th[9],  g2.y, v); v = fmaf(th[10], g2.z, v); v = fmaf(th[11], g2.w, v);
    v = fmaf(th[12], g3.x, v); v = fmaf(th[13], g3.y, v); v = fmaf(th[14], g3.z, v); v = fmaf(th[15], g3.w, v);
    embq[q] = v;
  }
  float di = 1.f/((hq ? ls1 : ls0) + EPSV);
  float4 ebv = *(const float4*)&eb[c0];
  float r0 = di*(ax + embq[0]) + ebv.x;
  float r1 = di*(ay + embq[1]) + ebv.y;
  float r2 = di*(az + embq[2]) + ebv.z;
  float r3 = di*(aw + embq[3]) + ebv.w;
  float p0 = __shfl_xor(r0, 32);
  float p1 = __shfl_xor(r1, 32);
  float p2 = __shfl_xor(r2, 32);
  float p3 = __shfl_xor(r3, 32);
  if (lane < 32){
    float4 bv = *(const float4*)&bias[c0];
    float4 v;
    v.x = 0.5f*(r0 + p0) + bv.x;
    v.y = 0.5f*(r1 + p1) + bv.y;
    v.z = 0.5f*(r2 + p2) + bv.z;
    v.w = 0.5f*(r3 + p3) + bv.w;
    if (relu){
      v.x = fmaxf(v.x, 0.f); v.y = fmaxf(v.y, 0.f);
      v.z = fmaxf(v.z, 0.f); v.w = fmaxf(v.w, 0.f);
    }
    *(float4*)&out[(size_t)n*DD + c0] = v;
  }
}

extern "C" void kernel_launch(void* const* d_in, const int* in_sizes, int n_in,
                              void* d_out, int out_size, void* d_ws, size_t ws_size,
                              hipStream_t stream){
  const float* x       = (const float*)d_in[0];
  const int*   eidx    = (const int*)d_in[1];
  const float* eattr   = (const float*)d_in[2];
  const float* weights = (const float*)d_in[3];
  const float* atts    = (const float*)d_in[4];
  const float* biases  = (const float*)d_in[5];
  const float* edge_ws = (const float*)d_in[6];
  const float* edge_bs = (const float*)d_in[7];
  const int N = in_sizes[0]/DD;
  const int E = in_sizes[1]/2;
  const int Etot = E + N;
  const int* src = eidx;
  const int* dst = eidx + E;

  char* p = (char*)d_ws;
  auto alloc = [&](size_t bytes){ void* r = (void*)p; p += (bytes + 255) & ~(size_t)255; return r; };
  float*         hA      = (float*)alloc((size_t)N*DD*4);
  float*         hB      = (float*)alloc((size_t)N*DD*4);
  unsigned char* xw8     = (unsigned char*)alloc((size_t)N*HD);
  float*         sbuf    = (float*)alloc((size_t)N*4*4);      // aliases counts/cursor during build
  int*           starts  = (int*)alloc((size_t)(N+1)*4);
  int*           srcC    = (int*)alloc((size_t)Etot*4);
  int*           eids    = (int*)alloc((size_t)Etot*4);
  __half*        attrC16 = (__half*)alloc((size_t)Etot*FF*2);
  float*         attrdot = (float*)alloc((size_t)5*Etot*2*4);
  __half*        wh      = (__half*)alloc((size_t)5*DD*HD*2);
  float*         c5      = (float*)alloc(5*34*4);

  int* counts = (int*)sbuf;                       // build-phase alias
  int* cursor = (int*)((char*)sbuf + 65536);      // build-phase alias

  const int ebl = (Etot + 255)/256;

  // CSR build (layer-invariant) + constants + W fp16 + attr precompute
  (void)hipMemsetAsync(counts, 0, (size_t)N*4, stream);
  k_hist_prec<<<ebl+165, 256, 0, stream>>>(dst, counts, atts, edge_ws, edge_bs, weights,
                                           c5, wh, E, Etot, ebl);
  k_scan<<<1, 1024, 0, stream>>>(counts, starts, cursor, N, Etot);
  k_scatter<<<ebl, 256, 0, stream>>>(dst, cursor, eids, E, Etot);
  k_gather_csr<<<ebl, 256, 0, stream>>>(eids, src, eattr, c5, srcC, attrC16, attrdot, E, Etot);

  const float* hin = x;
  for (int l = 0; l < 5; l++){
    const __half* Whl = wh + (size_t)l*DD*HD;
    const float* att = atts    + (size_t)l*HEADS*2*DD;
    const float* b   = biases  + (size_t)l*DD;
    const float* ew  = edge_ws + (size_t)l*HD*FF;
    const float* eb  = edge_bs + (size_t)l*HD;
    const float* c   = c5 + (size_t)l*34;
    const float* adL = attrdot + (size_t)l*Etot*2;
    float* hout = (l == 4) ? (float*)d_out : ((l & 1) ? hB : hA);
    int relu = (l < 4) ? 1 : 0;

    k_gemm_xw<<<(N+15)/16, 256, 0, stream>>>(hin, Whl, att, xw8, sbuf, N);
    k_aggr<<<(N+3)/4, 256, 0, stream>>>(starts, srcC, attrC16, adL, sbuf, c, xw8, ew, eb, b, hout, N, relu);

    hin = hout;
  }
}